// Round 14
// baseline (313.876 us; speedup 1.0000x reference)
//
#include <hip/hip_runtime.h>

#define N_NODES 100000
#define N_EDGES 3200000
#define N_GRAPHS 2048
#define SSH 8                       // 256 dst nodes per superbucket
#define SSZ 256
#define NSB 391                     // ceil(100000/256)
#define FILL_BLOCKS 512
#define CHUNK 6250                  // N_EDGES / FILL_BLOCKS
#define NSL 49                      // src slices of 2048 nodes
#define NBIN (SSZ * NSL)            // 12544 bins (50KB LDS)
#define DBLK 2048                   // dst nodes per agg block
#define NDB 49                      // ceil(100000/2048)
#define SPLIT 8
#define NPAD (NDB * DBLK)           // 100352

__device__ __forceinline__ void gAtomAdd(float* p, float v) { unsafeAtomicAdd(p, v); }

// pidx: reorder slices so split p's slices (t ≡ p mod 8) are contiguous, ascending
__device__ __forceinline__ int slice_pidx(int t) {
  int p = t & 7;
  return (p ? 6 * p + 1 : 0) + (t >> 3);   // split sizes: 7,6,6,6,6,6,6,6
}

// ---------- pass 1: per-block superbucket histogram + reservation (proven) ----------
__global__ void kA_count(const int* __restrict__ dst, int* __restrict__ bcnt,
                         int* __restrict__ blockBase) {
  __shared__ int hist[NSB];
  int tid = threadIdx.x, blk = blockIdx.x;
  for (int i = tid; i < NSB; i += 256) hist[i] = 0;
  __syncthreads();
  int beg = blk * CHUNK, end = beg + CHUNK;
  for (int e = beg + tid; e < end; e += 256) atomicAdd(&hist[dst[e] >> SSH], 1);
  __syncthreads();
  for (int i = tid; i < NSB; i += 256) {
    int h = hist[i];
    if (h) blockBase[blk * NSB + i] = atomicAdd(&bcnt[i], h);
  }
}

// ---------- exclusive scan over NSB counts (proven) ----------
__global__ void k_bscan(const int* __restrict__ bcnt, int* __restrict__ sboffs) {
  __shared__ int sh[512];
  int tid = threadIdx.x;
  int v = (tid < NSB) ? bcnt[tid] : 0;
  sh[tid] = v;
  __syncthreads();
  for (int off = 1; off < 512; off <<= 1) {
    int t = (tid >= off) ? sh[tid - off] : 0;
    __syncthreads();
    sh[tid] += t;
    __syncthreads();
  }
  if (tid < NSB) sboffs[tid] = sh[tid] - v;
  if (tid == 0) sboffs[NSB] = N_EDGES;
}

// ---------- pass 2: scatter packed edges into superbucket segments (proven) ----------
__global__ void kB_fill(const int* __restrict__ src, const int* __restrict__ dst,
                        const int* __restrict__ sboffs, const int* __restrict__ blockBase,
                        unsigned* __restrict__ stage) {
  __shared__ int lbase[NSB];
  int tid = threadIdx.x, blk = blockIdx.x;
  for (int i = tid; i < NSB; i += 256) lbase[i] = sboffs[i] + blockBase[blk * NSB + i];
  __syncthreads();
  int beg = blk * CHUNK, end = beg + CHUNK;
  for (int e = beg + tid; e < end; e += 256) {
    int d = dst[e], s = src[e];
    int pos = atomicAdd(&lbase[d >> SSH], 1);
    stage[pos] = ((unsigned)s << SSH) | (unsigned)(d & (SSZ - 1));  // src:17 | dstloc:8
  }
}

// ---------- pass 3: per-superbucket (node, split-ordered slice) counting sort ----------
__global__ void kC_csr(const unsigned* __restrict__ stage, const int* __restrict__ sboffs,
                       const float* __restrict__ x, int* __restrict__ noffs,
                       int* __restrict__ noffsS, float* __restrict__ dinv,
                       float* __restrict__ xd8, int* __restrict__ csr) {
  __shared__ int bins[NBIN];                       // 50KB
  __shared__ int sc[SSZ];
  int b = blockIdx.x, tid = threadIdx.x;
  for (int i = tid; i < NBIN; i += 256) bins[i] = 0;
  __syncthreads();
  int beg = sboffs[b], end = sboffs[b + 1];
  for (int k = beg + tid; k < end; k += 256) {
    unsigned u = stage[k];
    int dl = u & (SSZ - 1), s = u >> SSH;
    atomicAdd(&bins[dl * NSL + slice_pidx(s >> 11)], 1);
  }
  __syncthreads();
  int tot = 0;
  for (int j = 0; j < NSL; j++) tot += bins[tid * NSL + j];
  sc[tid] = tot;
  __syncthreads();
  for (int off = 1; off < SSZ; off <<= 1) {        // inclusive scan over 256
    int t = (tid >= off) ? sc[tid - off] : 0;
    __syncthreads();
    sc[tid] += t;
    __syncthreads();
  }
  int excl = sc[tid] - tot;
  int node = b * SSZ + tid;
  if (node <= N_NODES) noffs[node] = beg + excl;
  if (node < N_NODES) {
    float di = rsqrtf((float)(tot + 1));           // +1 self-loop
    dinv[node] = di;
    float r[5];
#pragma unroll
    for (int c = 0; c < 5; c++) r[c] = x[node * 5 + c] * di;
    float4* xv = (float4*)xd8;
    xv[node * 2]     = make_float4(r[0], r[1], r[2], r[3]);
    xv[node * 2 + 1] = make_float4(r[4], 0.f, 0.f, 0.f);
  }
  int run = beg + excl;
  for (int j = 0; j < NSL; j++) {                  // per-bin exclusive offsets
    int p = (j == 0) ? 0 : ((j >= 7 && (j - 7) % 6 == 0) ? 1 + (j - 7) / 6 : -1);
    if (p >= 0 && node < N_NODES) noffsS[node * 8 + p] = run;
    int c = bins[tid * NSL + j];
    bins[tid * NSL + j] = run;
    run += c;
  }
  __syncthreads();
  for (int k = beg + tid; k < end; k += 256) {     // scatter
    unsigned u = stage[k];
    int dl = u & (SSZ - 1), s = u >> SSH;
    int pos = atomicAdd(&bins[dl * NSL + slice_pidx(s >> 11)], 1);
    csr[pos] = s;
  }
}

// ---------- tiled agg: stream slice into LDS, register-accumulate per node ----------
template <int NC>
__global__ void k_aggs(const int* __restrict__ csr, const int* __restrict__ noffs,
                       const int* __restrict__ noffsS, const float* __restrict__ tab,
                       float* __restrict__ partial) {
  constexpr int NCS = (NC == 5) ? 5 : 9;           // LDS row stride: banks spread
  extern __shared__ float slice[];                 // DBLK * NCS floats
  int bx = blockIdx.x;
  int db = bx >> 3, p = bx & 7;
  int base = db * DBLK;
  int tid = threadIdx.x;                           // 512 threads, 4 nodes each
  int kcur[4], kend[4];
  float acc[4][NC];
#pragma unroll
  for (int i = 0; i < 4; i++) {
    int n = base + i * 512 + tid;
    if (n < N_NODES) {
      kcur[i] = noffsS[n * 8 + p];
      kend[i] = (p < 7) ? noffsS[n * 8 + p + 1] : noffs[n + 1];
    } else { kcur[i] = 0; kend[i] = 0; }
#pragma unroll
    for (int c = 0; c < NC; c++) acc[i][c] = 0.f;
  }
  for (int t = p; t < NSL; t += SPLIT) {
    __syncthreads();                               // prior slice readers done
    int gbase = t << 11;
    if (NC == 8) {
      for (int f = tid; f < DBLK * 2; f += 512) {  // coalesced 16B/lane stream
        int r = f >> 1, h = f & 1;
        int gr = gbase + r;
        float4 v = (gr < N_NODES) ? ((const float4*)(tab + (size_t)gr * 8))[h]
                                  : make_float4(0.f, 0.f, 0.f, 0.f);
        float* dp = slice + r * 9 + h * 4;
        dp[0] = v.x; dp[1] = v.y; dp[2] = v.z; dp[3] = v.w;
      }
    } else {
      for (int r = tid; r < DBLK; r += 512) {
        int gr = gbase + r;
        float4 v = make_float4(0.f, 0.f, 0.f, 0.f);
        float c4 = 0.f;
        if (gr < N_NODES) {
          v = ((const float4*)(tab + (size_t)gr * 8))[0];
          c4 = tab[gr * 8 + 4];
        }
        float* dp = slice + r * 5;
        dp[0] = v.x; dp[1] = v.y; dp[2] = v.z; dp[3] = v.w; dp[4] = c4;
      }
    }
    __syncthreads();                               // slice visible
#pragma unroll
    for (int i = 0; i < 4; i++) {
      int k = kcur[i], ke = kend[i];
      while (k < ke) {                             // contiguous sub-run, slice-ascending
        int s = csr[k];
        if ((s >> 11) != t) break;
        const float* sp = slice + (s & (DBLK - 1)) * NCS;
#pragma unroll
        for (int c = 0; c < NC; c++) acc[i][c] += sp[c];
        k++;
      }
      kcur[i] = k;
    }
  }
#pragma unroll
  for (int i = 0; i < 4; i++) {
    int n = base + i * 512 + tid;
    if (n < NPAD) {
      float* pp = partial + ((size_t)p * NPAD + n) * 8;
#pragma unroll
      for (int c = 0; c < NC; c++) pp[c] = acc[i][c];
    }
  }
}

// ---------- layer-1 epilogue: merge partials + self-loop, fused MLP (proven r11) ----------
__global__ void k_mlp(const float* __restrict__ partial, const float* __restrict__ xd8,
                      const float* __restrict__ dinv, const float* __restrict__ W1,
                      const float* __restrict__ b1, const float* __restrict__ W2,
                      float* __restrict__ g2) {
  __shared__ float w1[150], bb1[30], w2[240];
  int tid = threadIdx.x;
  for (int i = tid; i < 150; i += 256) w1[i] = W1[i];
  for (int i = tid; i < 30; i += 256) bb1[i] = b1[i];
  for (int i = tid; i < 240; i += 256) w2[i] = W2[i];
  __syncthreads();
  int n = blockIdx.x * 256 + tid;
  if (n >= N_NODES) return;
  float di = dinv[n];
  float4 s03 = ((const float4*)xd8)[n * 2];
  float s4v = xd8[n * 8 + 4];
#pragma unroll
  for (int p = 0; p < SPLIT; p++) {
    const float* pp = partial + ((size_t)p * NPAD + n) * 8;
    float4 q = ((const float4*)pp)[0];
    s03.x += q.x; s03.y += q.y; s03.z += q.z; s03.w += q.w;
    s4v += pp[4];
  }
  float t[5] = {s03.x * di, s03.y * di, s03.z * di, s03.w * di, s4v * di};
  float h[30];
#pragma unroll
  for (int j = 0; j < 30; j++) h[j] = bb1[j];
#pragma unroll
  for (int k = 0; k < 5; k++)
#pragma unroll
    for (int j = 0; j < 30; j++) h[j] += t[k] * w1[k * 30 + j];
  float g[8] = {0, 0, 0, 0, 0, 0, 0, 0};
#pragma unroll
  for (int j = 0; j < 30; j++) {
    float hj = fmaxf(h[j], 0.f);
#pragma unroll
    for (int c = 0; c < 8; c++) g[c] += hj * w2[j * 8 + c];
  }
  float4* gv = (float4*)g2;
  gv[n * 2]     = make_float4(g[0] * di, g[1] * di, g[2] * di, g[3] * di);
  gv[n * 2 + 1] = make_float4(g[4] * di, g[5] * di, g[6] * di, g[7] * di);
}

// ---------- layer-2 epilogue: merge partials + bias + pooling (proven r11) ----------
__global__ void k_out(const float* __restrict__ partial, const float* __restrict__ g2,
                      const float* __restrict__ dinv, const float* __restrict__ b2,
                      const int* __restrict__ batch, float* __restrict__ gsum) {
  __shared__ float gpool[64 * 8];
  __shared__ float bb2[8];
  __shared__ int batch0s;
  int blk = blockIdx.x, tid = threadIdx.x;         // 512 threads
  for (int i = tid; i < 64 * 8; i += 512) gpool[i] = 0.f;
  if (tid < 8) bb2[tid] = b2[tid];
  if (tid == 0) {
    int n0 = blk * 512;
    batch0s = batch[n0 < N_NODES ? n0 : (N_NODES - 1)];
  }
  __syncthreads();
  int n = blk * 512 + tid;
  int batch0 = batch0s;
  if (n < N_NODES) {
    float di = dinv[n];
    int gid = batch[n], goff = gid - batch0;
    float4 s03 = ((const float4*)g2)[n * 2];
    float4 s47 = ((const float4*)g2)[n * 2 + 1];
#pragma unroll
    for (int p = 0; p < SPLIT; p++) {
      const float4* pp = (const float4*)(partial + ((size_t)p * NPAD + n) * 8);
      float4 qa = pp[0], qb = pp[1];
      s03.x += qa.x; s03.y += qa.y; s03.z += qa.z; s03.w += qa.w;
      s47.x += qb.x; s47.y += qb.y; s47.z += qb.z; s47.w += qb.w;
    }
    float val[8] = {di * s03.x + bb2[0], di * s03.y + bb2[1], di * s03.z + bb2[2],
                    di * s03.w + bb2[3], di * s47.x + bb2[4], di * s47.y + bb2[5],
                    di * s47.z + bb2[6], di * s47.w + bb2[7]};
#pragma unroll
    for (int c = 0; c < 8; c++) {
      if (goff < 64) atomicAdd(&gpool[goff * 8 + c], val[c]);
      else           gAtomAdd(&gsum[gid * 8 + c], val[c]);
    }
  }
  __syncthreads();
  for (int i = tid; i < 64 * 8; i += 512) {
    int gid = batch0 + (i >> 3);
    float v = gpool[i];
    if (gid < N_GRAPHS && v != 0.f) gAtomAdd(&gsum[gid * 8 + (i & 7)], v);
  }
}

// ---------- mean divide (proven) ----------
__global__ void k_final(const float* __restrict__ gsum, const int* __restrict__ batch,
                        float* __restrict__ out) {
  int i = blockIdx.x * 256 + threadIdx.x;
  if (i >= N_GRAPHS * 8) return;
  int g = i >> 3;
  int lo = 0, hi = N_NODES;
  while (lo < hi) { int m = (lo + hi) >> 1; if (batch[m] < g) lo = m + 1; else hi = m; }
  int lo2 = lo, hi2 = N_NODES;
  while (lo2 < hi2) { int m = (lo2 + hi2) >> 1; if (batch[m] <= g) lo2 = m + 1; else hi2 = m; }
  float c = (float)(lo2 - lo);
  out[i] = gsum[i] / fmaxf(c, 1.f);
}

extern "C" void kernel_launch(void* const* d_in, const int* in_sizes, int n_in,
                              void* d_out, int out_size, void* d_ws, size_t ws_size,
                              hipStream_t stream) {
  const float* x    = (const float*)d_in[0];
  const int* ei     = (const int*)d_in[1];
  const int* batch  = (const int*)d_in[2];
  const float* W1   = (const float*)d_in[3];
  const float* b1   = (const float*)d_in[4];
  const float* W2   = (const float*)d_in[5];
  const float* b2   = (const float*)d_in[6];
  const int* srcp = ei;
  const int* dstp = ei + N_EDGES;
  float* out = (float*)d_out;

  // workspace carve (~49 MB; partial overlays blockBase+stage which die after kC)
  char* base = (char*)d_ws;
  size_t o = 0;
  auto carve = [&](size_t bytes) -> char* {
    char* p = base + o;
    o += (bytes + 255) & ~(size_t)255;
    return p;
  };
  size_t partial_sz = (size_t)SPLIT * NPAD * 8 * 4;        // 25.7 MB
  char* region     = carve(partial_sz);
  int* blockBase   = (int*)region;                          // 0.8 MB, dead after kB
  unsigned* stage  = (unsigned*)(region + (size_t)FILL_BLOCKS * NSB * 4); // dead after kC
  float* partial   = (float*)region;                        // first written by k_aggs<5>
  int* bcnt        = (int*)carve((size_t)NSB * 4);
  int* sboffs      = (int*)carve((size_t)(NSB + 1) * 4);
  int* csr         = (int*)carve((size_t)N_EDGES * 4);
  int* noffs       = (int*)carve((size_t)(N_NODES + 2) * 4);
  int* noffsS      = (int*)carve((size_t)N_NODES * 8 * 4);
  float* dinv      = (float*)carve((size_t)N_NODES * 4);
  float* xd8       = (float*)carve((size_t)N_NODES * 8 * 4);
  float* g2        = (float*)carve((size_t)N_NODES * 8 * 4);
  float* gsum      = (float*)carve((size_t)N_GRAPHS * 8 * 4);

  hipFuncSetAttribute(reinterpret_cast<const void*>(&k_aggs<8>),
                      hipFuncAttributeMaxDynamicSharedMemorySize, DBLK * 9 * 4);
  hipFuncSetAttribute(reinterpret_cast<const void*>(&k_aggs<5>),
                      hipFuncAttributeMaxDynamicSharedMemorySize, DBLK * 5 * 4);

  hipMemsetAsync(bcnt, 0, (size_t)NSB * 4, stream);
  hipMemsetAsync(gsum, 0, (size_t)N_GRAPHS * 8 * 4, stream);

  kA_count<<<FILL_BLOCKS, 256, 0, stream>>>(dstp, bcnt, blockBase);
  k_bscan<<<1, 512, 0, stream>>>(bcnt, sboffs);
  kB_fill<<<FILL_BLOCKS, 256, 0, stream>>>(srcp, dstp, sboffs, blockBase, stage);
  kC_csr<<<NSB, 256, 0, stream>>>(stage, sboffs, x, noffs, noffsS, dinv, xd8, csr);
  k_aggs<5><<<NDB * SPLIT, 512, DBLK * 5 * 4, stream>>>(csr, noffs, noffsS, xd8, partial);
  k_mlp<<<(N_NODES + 255) / 256, 256, 0, stream>>>(partial, xd8, dinv, W1, b1, W2, g2);
  k_aggs<8><<<NDB * SPLIT, 512, DBLK * 9 * 4, stream>>>(csr, noffs, noffsS, g2, partial);
  k_out<<<(N_NODES + 511) / 512, 512, 0, stream>>>(partial, g2, dinv, b2, batch, gsum);
  k_final<<<64, 256, 0, stream>>>(gsum, batch, out);
}